// Round 1
// baseline (391.149 us; speedup 1.0000x reference)
//
#include <hip/hip_runtime.h>
#include <hip/hip_bf16.h>

using bf16 = __hip_bfloat16;
typedef __attribute__((ext_vector_type(8))) short short8;
typedef __attribute__((ext_vector_type(4))) float f32x4;

static constexpr int Bc = 4, Lc = 2048, Sc = 1024;
static constexpr int DModel = 1024;

__device__ __forceinline__ void gload16(const void* g, void* l) {
  __builtin_amdgcn_global_load_lds((const __attribute__((address_space(1))) void*)g,
                                   (__attribute__((address_space(3))) void*)l,
                                   16, 0, 0);
}

// ---------------- conversion / transpose kernels ----------------
__global__ void cvt_f32_to_bf16(const float* __restrict__ in, bf16* __restrict__ out, long n) {
  long i = ((long)blockIdx.x * blockDim.x + threadIdx.x) * 4;
  long stride = (long)gridDim.x * blockDim.x * 4;
  for (; i < n; i += stride) {
    float4 v = *reinterpret_cast<const float4*>(in + i);
    alignas(8) bf16 t[4] = {__float2bfloat16(v.x), __float2bfloat16(v.y),
                            __float2bfloat16(v.z), __float2bfloat16(v.w)};
    *reinterpret_cast<ushort4*>(out + i) = *reinterpret_cast<const ushort4*>(t);
  }
}

// in: f32 [R][C] -> out: bf16 [C][R]
__global__ __launch_bounds__(256) void transpose_cvt_f32(const float* __restrict__ in,
                                                         bf16* __restrict__ out,
                                                         int R, int C) {
  __shared__ bf16 tile[32][33];
  int tx = threadIdx.x & 31, ty = threadIdx.x >> 5;
  int r0 = blockIdx.y * 32, c0 = blockIdx.x * 32;
#pragma unroll
  for (int i = 0; i < 32; i += 8)
    tile[ty + i][tx] = __float2bfloat16(in[(long)(r0 + ty + i) * C + c0 + tx]);
  __syncthreads();
#pragma unroll
  for (int i = 0; i < 32; i += 8)
    out[(long)(c0 + ty + i) * R + r0 + tx] = tile[tx][ty + i];
}

// batched bf16 transpose: in [Z][R][C] -> out [Z][C][R]
__global__ __launch_bounds__(256) void transpose_bf16_batched(const bf16* __restrict__ in,
                                                              bf16* __restrict__ out,
                                                              int R, int C) {
  __shared__ bf16 tile[32][33];
  long base = (long)blockIdx.z * R * C;
  int tx = threadIdx.x & 31, ty = threadIdx.x >> 5;
  int r0 = blockIdx.y * 32, c0 = blockIdx.x * 32;
#pragma unroll
  for (int i = 0; i < 32; i += 8)
    tile[ty + i][tx] = in[base + (long)(r0 + ty + i) * C + c0 + tx];
  __syncthreads();
#pragma unroll
  for (int i = 0; i < 32; i += 8)
    out[base + (long)(c0 + ty + i) * R + r0 + tx] = tile[tx][ty + i];
}

// ---------------- GEMM: C[M][N] = A[M][K] * Bt[N][K]^T + bias ----------------
// 128x128 tile, BK=64, 4 waves (2x2), 16x16x32 bf16 MFMA.
// LDS tiles stored XOR-swizzled (byte ^= (row&7)<<4) via source-side pre-swizzle
// so global_load_lds stays linear and ds_read_b128 is conflict-free (2-way).
__global__ __launch_bounds__(256) void gemm_bt(const bf16* __restrict__ A,
                                               const bf16* __restrict__ Bt,
                                               const float* __restrict__ bias,
                                               bf16* __restrict__ Cb,
                                               float* __restrict__ Cf,
                                               int M, int N, int K) {
  __shared__ bf16 As[128 * 64];
  __shared__ bf16 Bs[128 * 64];
  const int tid = threadIdx.x;
  const int lane = tid & 63, g = lane >> 4, lm = lane & 15;
  const int wid = tid >> 6, wr = wid >> 1, wc = wid & 1;
  const long brow = (long)blockIdx.y * 128, bcol = (long)blockIdx.x * 128;
  const bf16* Ab = A + brow * K;
  const bf16* Bb = Bt + bcol * K;

  f32x4 zero = {0.f, 0.f, 0.f, 0.f};
  f32x4 acc[4][4];
#pragma unroll
  for (int i = 0; i < 4; ++i)
#pragma unroll
    for (int j = 0; j < 4; ++j) acc[i][j] = zero;

  const char* Asc = (const char*)As;
  const char* Bsc = (const char*)Bs;

  for (int k0 = 0; k0 < K; k0 += 64) {
    __syncthreads();  // all waves done reading previous tile
#pragma unroll
    for (int t = 0; t < 4; ++t) {
      int sl = tid + t * 256;          // slot 0..1023, 16B each
      int row = sl >> 3;               // tile row 0..127
      int kg = (sl & 7) ^ (row & 7);   // source pre-swizzle
      gload16(Ab + (long)row * K + k0 + kg * 8, (char*)As + sl * 16);
      gload16(Bb + (long)row * K + k0 + kg * 8, (char*)Bs + sl * 16);
    }
    __syncthreads();  // drains vmcnt; LDS tiles ready
#pragma unroll
    for (int ks = 0; ks < 2; ++ks) {
      short8 af[4], bfv[4];
#pragma unroll
      for (int mi = 0; mi < 4; ++mi) {
        int m = wr * 64 + mi * 16 + lm;
        af[mi] = *reinterpret_cast<const short8*>(
            Asc + ((m * 128 + ks * 64 + g * 16) ^ ((m & 7) << 4)));
      }
#pragma unroll
      for (int ni = 0; ni < 4; ++ni) {
        int n = wc * 64 + ni * 16 + lm;
        bfv[ni] = *reinterpret_cast<const short8*>(
            Bsc + ((n * 128 + ks * 64 + g * 16) ^ ((n & 7) << 4)));
      }
#pragma unroll
      for (int mi = 0; mi < 4; ++mi)
#pragma unroll
        for (int ni = 0; ni < 4; ++ni)
          acc[mi][ni] = __builtin_amdgcn_mfma_f32_16x16x32_bf16(af[mi], bfv[ni], acc[mi][ni], 0, 0, 0);
    }
  }

  // epilogue: D layout col = lane&15, row = (lane>>4)*4 + r
#pragma unroll
  for (int ni = 0; ni < 4; ++ni) {
    long n = bcol + wc * 64 + ni * 16 + lm;
    float bv = bias ? bias[n] : 0.f;
#pragma unroll
    for (int mi = 0; mi < 4; ++mi) {
      long m0 = brow + wr * 64 + mi * 16 + g * 4;
#pragma unroll
      for (int r = 0; r < 4; ++r) {
        float o = acc[mi][ni][r] + bv;
        if (Cb) Cb[(m0 + r) * N + n] = __float2bfloat16(o);
        else    Cf[(m0 + r) * N + n] = o;
      }
    }
  }
}

// ---------------- fused flash attention ----------------
// One block = one (b,h), 64 q rows. 4 waves x 16 q rows each.
// q: [B*L][1024] bf16, k: [B*S][1024] bf16, vT: [B][1024][S] bf16 (head-col major)
__global__ __launch_bounds__(256) void attn_fused(const bf16* __restrict__ q,
                                                  const bf16* __restrict__ k,
                                                  const bf16* __restrict__ vT,
                                                  bf16* __restrict__ o) {
  constexpr float C2 = 0.18033688011112042f;  // (1/8) * log2(e)
  __shared__ bf16 Kl[64 * 64];      // [s][e], swizzled
  __shared__ bf16 Vl[64 * 64];      // [e][s], swizzled
  __shared__ bf16 Pl[4][16 * 64];   // per-wave [q][s], swizzled
  const int tid = threadIdx.x;
  const int lane = tid & 63, g = lane >> 4, lm = lane & 15;
  const int wid = tid >> 6;
  const int b = blockIdx.y >> 4, h = blockIdx.y & 15;
  const int qbase = blockIdx.x * 64 + wid * 16;

  const bf16* qrow = q + (long)(b * Lc + qbase + lm) * DModel + h * 64;
  short8 qa0 = *reinterpret_cast<const short8*>(qrow + g * 8);
  short8 qa1 = *reinterpret_cast<const short8*>(qrow + 32 + g * 8);

  const bf16* kbase = k + (long)b * Sc * DModel + h * 64;
  const bf16* vbase = vT + ((long)b * DModel + h * 64) * Sc;

  f32x4 zero = {0.f, 0.f, 0.f, 0.f};
  f32x4 accO[4];
#pragma unroll
  for (int i = 0; i < 4; ++i) accO[i] = zero;
  float mst[4] = {-1e30f, -1e30f, -1e30f, -1e30f};
  float lst[4] = {0.f, 0.f, 0.f, 0.f};

  const char* Klc = (const char*)Kl;
  const char* Vlc = (const char*)Vl;
  char* Plc = (char*)Pl + wid * (16 * 64 * 2);

  for (int sc0 = 0; sc0 < Sc; sc0 += 64) {
    __syncthreads();  // everyone done reading previous K/V tile
#pragma unroll
    for (int t = 0; t < 2; ++t) {
      int sl = tid + t * 256;
      int row = sl >> 3;               // K: s-row / V: e-row (0..63)
      int cg = (sl & 7) ^ (row & 7);   // source pre-swizzle
      gload16(kbase + (long)(sc0 + row) * DModel + cg * 8, (char*)Kl + sl * 16);
      gload16(vbase + (long)row * Sc + sc0 + cg * 8, (char*)Vl + sl * 16);
    }
    __syncthreads();

    // QK^T: D rows = q (4g+r), cols = s (st*16+lm)
    f32x4 scv[4];
#pragma unroll
    for (int st = 0; st < 4; ++st) {
      int s = st * 16 + lm;
      int sw = (s & 7) << 4;
      short8 kb0 = *reinterpret_cast<const short8*>(Klc + ((s * 128 + g * 16) ^ sw));
      short8 kb1 = *reinterpret_cast<const short8*>(Klc + ((s * 128 + 64 + g * 16) ^ sw));
      f32x4 z = zero;
      z = __builtin_amdgcn_mfma_f32_16x16x32_bf16(qa0, kb0, z, 0, 0, 0);
      z = __builtin_amdgcn_mfma_f32_16x16x32_bf16(qa1, kb1, z, 0, 0, 0);
      scv[st] = z;
    }

    // online softmax (wave-parallel; state per q-row replicated across 16 lanes)
    float mnew[4], corr[4];
#pragma unroll
    for (int r = 0; r < 4; ++r) {
      float mx = fmaxf(fmaxf(scv[0][r], scv[1][r]), fmaxf(scv[2][r], scv[3][r]));
      mx = fmaxf(mx, __shfl_xor(mx, 1));
      mx = fmaxf(mx, __shfl_xor(mx, 2));
      mx = fmaxf(mx, __shfl_xor(mx, 4));
      mx = fmaxf(mx, __shfl_xor(mx, 8));
      mnew[r] = fmaxf(mst[r], mx);
      corr[r] = __builtin_amdgcn_exp2f((mst[r] - mnew[r]) * C2);
      mst[r] = mnew[r];
    }
#pragma unroll
    for (int r = 0; r < 4; ++r) {
      int qq = g * 4 + r;
      int swp = (qq & 7) << 4;
      float rs = 0.f;
#pragma unroll
      for (int st = 0; st < 4; ++st) {
        float p = __builtin_amdgcn_exp2f((scv[st][r] - mnew[r]) * C2);
        rs += p;
        *reinterpret_cast<bf16*>(Plc + ((qq * 128 + (st * 16 + lm) * 2) ^ swp)) =
            __float2bfloat16(p);
      }
      rs += __shfl_xor(rs, 1);
      rs += __shfl_xor(rs, 2);
      rs += __shfl_xor(rs, 4);
      rs += __shfl_xor(rs, 8);
      lst[r] = lst[r] * corr[r] + rs;
#pragma unroll
      for (int et = 0; et < 4; ++et) accO[et][r] *= corr[r];
    }

    // PV: out[q][e] += P[q][s] * V[s][e];  A = P (from per-wave LDS), B = V^T tile
#pragma unroll
    for (int sk = 0; sk < 2; ++sk) {
      short8 pa = *reinterpret_cast<const short8*>(
          Plc + ((lm * 128 + sk * 64 + g * 16) ^ ((lm & 7) << 4)));
#pragma unroll
      for (int et = 0; et < 4; ++et) {
        int e = et * 16 + lm;
        short8 vb = *reinterpret_cast<const short8*>(
            Vlc + ((e * 128 + sk * 64 + g * 16) ^ ((e & 7) << 4)));
        accO[et] = __builtin_amdgcn_mfma_f32_16x16x32_bf16(pa, vb, accO[et], 0, 0, 0);
      }
    }
  }

#pragma unroll
  for (int r = 0; r < 4; ++r) {
    float inv = 1.0f / lst[r];
    long row = (long)(b * Lc + qbase + g * 4 + r);
#pragma unroll
    for (int et = 0; et < 4; ++et)
      o[row * DModel + h * 64 + et * 16 + lm] = __float2bfloat16(accO[et][r] * inv);
  }
}

// ---------------- host launch ----------------
extern "C" void kernel_launch(void* const* d_in, const int* in_sizes, int n_in,
                              void* d_out, int out_size, void* d_ws, size_t ws_size,
                              hipStream_t stream) {
  const float* tgt = (const float*)d_in[0];
  const float* src = (const float*)d_in[1];
  const float* val = (const float*)d_in[2];
  const float* Wq  = (const float*)d_in[3];
  const float* bq  = (const float*)d_in[4];
  const float* Wk  = (const float*)d_in[5];
  const float* bk  = (const float*)d_in[6];
  const float* Wv  = (const float*)d_in[7];
  const float* bv  = (const float*)d_in[8];
  const float* Wo  = (const float*)d_in[9];
  const float* bo  = (const float*)d_in[10];
  float* out = (float*)d_out;
  char* ws = (char*)d_ws;

  if (ws_size < (100ul << 20)) return;  // need 100 MB scratch

  bf16* WqT  = (bf16*)(ws + (0l  << 20));  // 2 MB  [1024][1024]
  bf16* WkT  = (bf16*)(ws + (2l  << 20));  // 8 MB  [1024][4096] (reused as v later)
  bf16* WvT  = (bf16*)(ws + (10l << 20));  // 8 MB  [1024][4096]
  bf16* WoT  = (bf16*)(ws + (18l << 20));  // 2 MB  [1024][1024]
  bf16* tgtb = (bf16*)(ws + (20l << 20));  // 16 MB [8192][1024] (reused as attn out)
  bf16* srcb = (bf16*)(ws + (36l << 20));  // 32 MB [4096][4096] (source, then value)
  bf16* qb   = (bf16*)(ws + (68l << 20));  // 16 MB [8192][1024]
  bf16* kb   = (bf16*)(ws + (84l << 20));  // 8 MB  [4096][1024]
  bf16* vTb  = (bf16*)(ws + (92l << 20));  // 8 MB  [4][1024][1024]  -> total 100 MB
  bf16* vb = WkT;      // v [4096][1024] aliases WkT (dead after K-proj GEMM)
  bf16* attnb = tgtb;  // attention output aliases target_bf16 (dead after Q GEMM)

  // weights -> bf16, transposed to [N][K]
  transpose_cvt_f32<<<dim3(32, 32),  256, 0, stream>>>(Wq, WqT, 1024, 1024);
  transpose_cvt_f32<<<dim3(32, 128), 256, 0, stream>>>(Wk, WkT, 4096, 1024);
  transpose_cvt_f32<<<dim3(32, 128), 256, 0, stream>>>(Wv, WvT, 4096, 1024);
  transpose_cvt_f32<<<dim3(32, 32),  256, 0, stream>>>(Wo, WoT, 1024, 1024);

  // Q = target @ Wq + bq
  cvt_f32_to_bf16<<<2048, 256, 0, stream>>>(tgt, tgtb, (long)8192 * 1024);
  gemm_bt<<<dim3(8, 64), 256, 0, stream>>>(tgtb, WqT, bq, qb, (float*)nullptr, 8192, 1024, 1024);

  // K = source @ Wk + bk
  cvt_f32_to_bf16<<<2048, 256, 0, stream>>>(src, srcb, (long)4096 * 4096);
  gemm_bt<<<dim3(8, 32), 256, 0, stream>>>(srcb, WkT, bk, kb, (float*)nullptr, 4096, 1024, 4096);

  // V = value @ Wv + bv  (value reuses srcb; v output reuses WkT)
  cvt_f32_to_bf16<<<2048, 256, 0, stream>>>(val, srcb, (long)4096 * 4096);
  gemm_bt<<<dim3(8, 32), 256, 0, stream>>>(srcb, WvT, bv, vb, (float*)nullptr, 4096, 1024, 4096);

  // vT[b][c][s] = v[b][s][c]
  transpose_bf16_batched<<<dim3(32, 32, 4), 256, 0, stream>>>(vb, vTb, 1024, 1024);

  // fused softmax(q k^T / sqrt(64)) v
  attn_fused<<<dim3(32, 64), 256, 0, stream>>>(qb, kb, vTb, attnb);

  // out = attn @ Wo + bo (f32 output)
  gemm_bt<<<dim3(8, 64), 256, 0, stream>>>(attnb, WoT, bo, (bf16*)nullptr, out, 8192, 1024, 1024);
}

// Round 2
// 274.621 us; speedup vs baseline: 1.4243x; 1.4243x over previous
//
#include <hip/hip_runtime.h>
#include <hip/hip_bf16.h>

using bf16 = __hip_bfloat16;
typedef __attribute__((ext_vector_type(8))) short short8;
typedef __attribute__((ext_vector_type(4))) float f32x4;

static constexpr int Bc = 4, Lc = 2048, Sc = 1024;
static constexpr int DModel = 1024;

__device__ __forceinline__ void gload16(const void* g, void* l) {
  __builtin_amdgcn_global_load_lds((const __attribute__((address_space(1))) void*)g,
                                   (__attribute__((address_space(3))) void*)l,
                                   16, 0, 0);
}

// ---------------- fused conversions ----------------
// three f32->bf16 ranges in one launch (counts in float4 units; zero-count ok)
__global__ void cvt3(const float* __restrict__ a, bf16* __restrict__ ao, long na4,
                     const float* __restrict__ b, bf16* __restrict__ bo, long nb4,
                     const float* __restrict__ c, bf16* __restrict__ co, long nc4) {
  long total = na4 + nb4 + nc4;
  long stride = (long)gridDim.x * blockDim.x;
  for (long i = (long)blockIdx.x * blockDim.x + threadIdx.x; i < total; i += stride) {
    const float* src; bf16* dst; long j;
    if (i < na4)            { src = a; dst = ao; j = i; }
    else if (i < na4 + nb4) { src = b; dst = bo; j = i - na4; }
    else                    { src = c; dst = co; j = i - na4 - nb4; }
    float4 v = reinterpret_cast<const float4*>(src)[j];
    alignas(8) bf16 t[4] = {__float2bfloat16(v.x), __float2bfloat16(v.y),
                            __float2bfloat16(v.z), __float2bfloat16(v.w)};
    reinterpret_cast<ushort4*>(dst)[j] = *reinterpret_cast<const ushort4*>(t);
  }
}

// all four weight transposes (f32 [R][C] -> bf16 [C][R]) in one launch
__global__ __launch_bounds__(256) void transpose_cvt_w(const float* __restrict__ Wq, bf16* __restrict__ WqT,
                                                       const float* __restrict__ Wk, bf16* __restrict__ WkT,
                                                       const float* __restrict__ Wv, bf16* __restrict__ WvT,
                                                       const float* __restrict__ Wo, bf16* __restrict__ WoT) {
  __shared__ bf16 tile[32][33];
  int bid = blockIdx.x;
  const float* in; bf16* out; int R, l;
  if (bid < 1024)      { in = Wq; out = WqT; R = 1024; l = bid; }
  else if (bid < 5120) { in = Wk; out = WkT; R = 4096; l = bid - 1024; }
  else if (bid < 9216) { in = Wv; out = WvT; R = 4096; l = bid - 5120; }
  else                 { in = Wo; out = WoT; R = 1024; l = bid - 9216; }
  const int C = 1024;
  int bx = l & 31, by = l >> 5;
  int tx = threadIdx.x & 31, ty = threadIdx.x >> 5;
  int r0 = by * 32, c0 = bx * 32;
#pragma unroll
  for (int i = 0; i < 32; i += 8)
    tile[ty + i][tx] = __float2bfloat16(in[(long)(r0 + ty + i) * C + c0 + tx]);
  __syncthreads();
#pragma unroll
  for (int i = 0; i < 32; i += 8)
    out[(long)(c0 + ty + i) * R + r0 + tx] = tile[tx][ty + i];
}

// batched bf16 transpose: in [Z][R][C] -> out [Z][C][R]
__global__ __launch_bounds__(256) void transpose_bf16_batched(const bf16* __restrict__ in,
                                                              bf16* __restrict__ out,
                                                              int R, int C) {
  __shared__ bf16 tile[32][33];
  long base = (long)blockIdx.z * R * C;
  int tx = threadIdx.x & 31, ty = threadIdx.x >> 5;
  int r0 = blockIdx.y * 32, c0 = blockIdx.x * 32;
#pragma unroll
  for (int i = 0; i < 32; i += 8)
    tile[ty + i][tx] = in[base + (long)(r0 + ty + i) * C + c0 + tx];
  __syncthreads();
#pragma unroll
  for (int i = 0; i < 32; i += 8)
    out[base + (long)(c0 + ty + i) * R + r0 + tx] = tile[tx][ty + i];
}

// ---------------- GEMM core: C[128x128 tile] = A[M][K] * Bt[N][K]^T + bias ----------------
__device__ __forceinline__ void gemm_core(const bf16* __restrict__ A, const bf16* __restrict__ Bt,
                                          const float* __restrict__ bias,
                                          bf16* __restrict__ Cb, float* __restrict__ Cf,
                                          int N, int K, int bx, int by,
                                          bf16* As, bf16* Bs) {
  const int tid = threadIdx.x;
  const int lane = tid & 63, g = lane >> 4, lm = lane & 15;
  const int wid = tid >> 6, wr = wid >> 1, wc = wid & 1;
  const long brow = (long)by * 128, bcol = (long)bx * 128;
  const bf16* Ab = A + brow * K;
  const bf16* Bb = Bt + bcol * K;

  f32x4 zero = {0.f, 0.f, 0.f, 0.f};
  f32x4 acc[4][4];
#pragma unroll
  for (int i = 0; i < 4; ++i)
#pragma unroll
    for (int j = 0; j < 4; ++j) acc[i][j] = zero;

  const char* Asc = (const char*)As;
  const char* Bsc = (const char*)Bs;

  for (int k0 = 0; k0 < K; k0 += 64) {
    __syncthreads();
#pragma unroll
    for (int t = 0; t < 4; ++t) {
      int sl = tid + t * 256;
      int row = sl >> 3;
      int kg = (sl & 7) ^ (row & 7);  // source pre-swizzle
      gload16(Ab + (long)row * K + k0 + kg * 8, (char*)As + sl * 16);
      gload16(Bb + (long)row * K + k0 + kg * 8, (char*)Bs + sl * 16);
    }
    __syncthreads();
#pragma unroll
    for (int ks = 0; ks < 2; ++ks) {
      short8 af[4], bfv[4];
#pragma unroll
      for (int mi = 0; mi < 4; ++mi) {
        int m = wr * 64 + mi * 16 + lm;
        af[mi] = *reinterpret_cast<const short8*>(
            Asc + ((m * 128 + ks * 64 + g * 16) ^ ((m & 7) << 4)));
      }
#pragma unroll
      for (int ni = 0; ni < 4; ++ni) {
        int n = wc * 64 + ni * 16 + lm;
        bfv[ni] = *reinterpret_cast<const short8*>(
            Bsc + ((n * 128 + ks * 64 + g * 16) ^ ((n & 7) << 4)));
      }
#pragma unroll
      for (int mi = 0; mi < 4; ++mi)
#pragma unroll
        for (int ni = 0; ni < 4; ++ni)
          acc[mi][ni] = __builtin_amdgcn_mfma_f32_16x16x32_bf16(af[mi], bfv[ni], acc[mi][ni], 0, 0, 0);
    }
  }

#pragma unroll
  for (int ni = 0; ni < 4; ++ni) {
    long n = bcol + wc * 64 + ni * 16 + lm;
    float bv = bias ? bias[n] : 0.f;
#pragma unroll
    for (int mi = 0; mi < 4; ++mi) {
      long m0 = brow + wr * 64 + mi * 16 + g * 4;
#pragma unroll
      for (int r = 0; r < 4; ++r) {
        float o = acc[mi][ni][r] + bv;
        if (Cb) Cb[(m0 + r) * N + n] = __float2bfloat16(o);
        else    Cf[(m0 + r) * N + n] = o;
      }
    }
  }
}

__global__ __launch_bounds__(256) void gemm_bt(const bf16* __restrict__ A,
                                               const bf16* __restrict__ Bt,
                                               const float* __restrict__ bias,
                                               bf16* __restrict__ Cb,
                                               float* __restrict__ Cf,
                                               int N, int K) {
  __shared__ bf16 As[128 * 64];
  __shared__ bf16 Bs[128 * 64];
  gemm_core(A, Bt, bias, Cb, Cf, N, K, blockIdx.x, blockIdx.y, As, Bs);
}

// Q/K/V projections fused into one launch; all N=1024; segment by linear block id.
__global__ __launch_bounds__(256) void gemm_qkv(
    const bf16* __restrict__ A0, const bf16* __restrict__ B0, const float* __restrict__ c0, bf16* __restrict__ C0, int K0, int nb0,
    const bf16* __restrict__ A1, const bf16* __restrict__ B1, const float* __restrict__ c1, bf16* __restrict__ C1, int K1, int nb1,
    const bf16* __restrict__ A2, const bf16* __restrict__ B2, const float* __restrict__ c2, bf16* __restrict__ C2, int K2) {
  __shared__ bf16 As[128 * 64];
  __shared__ bf16 Bs[128 * 64];
  int bid = blockIdx.x;
  const bf16 *A, *Bt; const float* bias; bf16* C; int K, l;
  if (bid < nb0)            { A = A0; Bt = B0; bias = c0; C = C0; K = K0; l = bid; }
  else if (bid < nb0 + nb1) { A = A1; Bt = B1; bias = c1; C = C1; K = K1; l = bid - nb0; }
  else                      { A = A2; Bt = B2; bias = c2; C = C2; K = K2; l = bid - nb0 - nb1; }
  gemm_core(A, Bt, bias, C, nullptr, 1024, K, l & 7, l >> 3, As, Bs);
}

// ---------------- fused flash attention ----------------
// One block = one (b,h), 64 q rows. 4 waves x 16 q rows each.
// Q pre-scaled by C2 = (1/8)*log2(e) so softmax uses exp2(scv - m) directly.
// Row-sum l computed via MFMA with all-ones B fragment (accL).
__global__ __launch_bounds__(256) void attn_fused(const bf16* __restrict__ q,
                                                  const bf16* __restrict__ k,
                                                  const bf16* __restrict__ vT,
                                                  bf16* __restrict__ o) {
  constexpr float C2 = 0.18033688011112042f;  // (1/8) * log2(e)
  constexpr float THR = 6.0f;                 // defer-max threshold (scaled units)
  __shared__ bf16 Kl[64 * 64];      // [s][e], swizzled
  __shared__ bf16 Vl[64 * 64];      // [e][s], swizzled
  __shared__ bf16 Pl[4][16 * 64];   // per-wave [q][s], swizzled
  const int tid = threadIdx.x;
  const int lane = tid & 63, g = lane >> 4, lm = lane & 15;
  const int wid = tid >> 6;
  const int b = blockIdx.y >> 4, h = blockIdx.y & 15;
  const int qbase = blockIdx.x * 64 + wid * 16;

  const bf16* qrow = q + (long)(b * Lc + qbase + lm) * DModel + h * 64;
  short8 qa0 = *reinterpret_cast<const short8*>(qrow + g * 8);
  short8 qa1 = *reinterpret_cast<const short8*>(qrow + 32 + g * 8);
  // pre-scale q fragments by C2 (bf16 -> f32 -> *C2 -> bf16)
#pragma unroll
  for (int j = 0; j < 8; ++j) {
    union { ushort u; bf16 h; } cv;
    cv.u = (ushort)qa0[j];
    bf16 s0 = __float2bfloat16(__bfloat162float(cv.h) * C2);
    qa0[j] = (short)*reinterpret_cast<ushort*>(&s0);
    cv.u = (ushort)qa1[j];
    bf16 s1 = __float2bfloat16(__bfloat162float(cv.h) * C2);
    qa1[j] = (short)*reinterpret_cast<ushort*>(&s1);
  }

  const bf16* kbase = k + (long)b * Sc * DModel + h * 64;
  const bf16* vbase = vT + ((long)b * DModel + h * 64) * Sc;

  f32x4 zero = {0.f, 0.f, 0.f, 0.f};
  f32x4 accO[4];
#pragma unroll
  for (int i = 0; i < 4; ++i) accO[i] = zero;
  f32x4 accL = zero;
  float mst[4] = {-1e30f, -1e30f, -1e30f, -1e30f};

  short8 vones;
#pragma unroll
  for (int j = 0; j < 8; ++j) vones[j] = (short)0x3F80;  // bf16 1.0

  const char* Klc = (const char*)Kl;
  const char* Vlc = (const char*)Vl;
  char* Plc = (char*)Pl + wid * (16 * 64 * 2);

  for (int sc0 = 0; sc0 < Sc; sc0 += 64) {
    __syncthreads();
#pragma unroll
    for (int t = 0; t < 2; ++t) {
      int sl = tid + t * 256;
      int row = sl >> 3;
      int cg = (sl & 7) ^ (row & 7);
      gload16(kbase + (long)(sc0 + row) * DModel + cg * 8, (char*)Kl + sl * 16);
      gload16(vbase + (long)row * Sc + sc0 + cg * 8, (char*)Vl + sl * 16);
    }
    __syncthreads();

    // QK^T (scaled): D rows = q (4g+r), cols = s (st*16+lm)
    f32x4 scv[4];
    __builtin_amdgcn_s_setprio(1);
#pragma unroll
    for (int st = 0; st < 4; ++st) {
      int s = st * 16 + lm;
      int sw = (s & 7) << 4;
      short8 kb0 = *reinterpret_cast<const short8*>(Klc + ((s * 128 + g * 16) ^ sw));
      short8 kb1 = *reinterpret_cast<const short8*>(Klc + ((s * 128 + 64 + g * 16) ^ sw));
      f32x4 z = zero;
      z = __builtin_amdgcn_mfma_f32_16x16x32_bf16(qa0, kb0, z, 0, 0, 0);
      z = __builtin_amdgcn_mfma_f32_16x16x32_bf16(qa1, kb1, z, 0, 0, 0);
      scv[st] = z;
    }
    __builtin_amdgcn_s_setprio(0);

    // online softmax with defer-max: rescale only if max grew past THR
    float pmax[4];
#pragma unroll
    for (int r = 0; r < 4; ++r)
      pmax[r] = fmaxf(fmaxf(scv[0][r], scv[1][r]), fmaxf(scv[2][r], scv[3][r]));
    int need = 0;
#pragma unroll
    for (int r = 0; r < 4; ++r) need |= (pmax[r] > mst[r] + THR) ? 1 : 0;
    if (__any(need)) {
#pragma unroll
      for (int r = 0; r < 4; ++r) {
        float mx = pmax[r];
        mx = fmaxf(mx, __shfl_xor(mx, 1));
        mx = fmaxf(mx, __shfl_xor(mx, 2));
        mx = fmaxf(mx, __shfl_xor(mx, 4));
        mx = fmaxf(mx, __shfl_xor(mx, 8));
        float mnew = fmaxf(mst[r], mx);
        float corr = __builtin_amdgcn_exp2f(mst[r] - mnew);
        mst[r] = mnew;
        accL[r] *= corr;
#pragma unroll
        for (int et = 0; et < 4; ++et) accO[et][r] *= corr;
      }
    }
#pragma unroll
    for (int r = 0; r < 4; ++r) {
      int qq = g * 4 + r;
      int swp = (qq & 7) << 4;
#pragma unroll
      for (int st = 0; st < 4; ++st) {
        float p = __builtin_amdgcn_exp2f(scv[st][r] - mst[r]);
        *reinterpret_cast<bf16*>(Plc + ((qq * 128 + (st * 16 + lm) * 2) ^ swp)) =
            __float2bfloat16(p);
      }
    }

    // PV: out[q][e] += P[q][s] * V[s][e]; l += P[q][s] * 1 (via ones fragment)
    __builtin_amdgcn_s_setprio(1);
#pragma unroll
    for (int sk = 0; sk < 2; ++sk) {
      short8 pa = *reinterpret_cast<const short8*>(
          Plc + ((lm * 128 + sk * 64 + g * 16) ^ ((lm & 7) << 4)));
      accL = __builtin_amdgcn_mfma_f32_16x16x32_bf16(pa, vones, accL, 0, 0, 0);
#pragma unroll
      for (int et = 0; et < 4; ++et) {
        int e = et * 16 + lm;
        short8 vb = *reinterpret_cast<const short8*>(
            Vlc + ((e * 128 + sk * 64 + g * 16) ^ ((e & 7) << 4)));
        accO[et] = __builtin_amdgcn_mfma_f32_16x16x32_bf16(pa, vb, accO[et], 0, 0, 0);
      }
    }
    __builtin_amdgcn_s_setprio(0);
  }

#pragma unroll
  for (int r = 0; r < 4; ++r) {
    float inv = 1.0f / accL[r];
    long row = (long)(b * Lc + qbase + g * 4 + r);
#pragma unroll
    for (int et = 0; et < 4; ++et)
      o[row * DModel + h * 64 + et * 16 + lm] = __float2bfloat16(accO[et][r] * inv);
  }
}

// ---------------- host launch ----------------
extern "C" void kernel_launch(void* const* d_in, const int* in_sizes, int n_in,
                              void* d_out, int out_size, void* d_ws, size_t ws_size,
                              hipStream_t stream) {
  const float* tgt = (const float*)d_in[0];
  const float* src = (const float*)d_in[1];
  const float* val = (const float*)d_in[2];
  const float* Wq  = (const float*)d_in[3];
  const float* bq  = (const float*)d_in[4];
  const float* Wk  = (const float*)d_in[5];
  const float* bk  = (const float*)d_in[6];
  const float* Wv  = (const float*)d_in[7];
  const float* bv  = (const float*)d_in[8];
  const float* Wo  = (const float*)d_in[9];
  const float* bo  = (const float*)d_in[10];
  float* out = (float*)d_out;
  char* ws = (char*)d_ws;

  const long n4_tgt = (long)8192 * 1024 / 4;   // 2,097,152
  const long n4_sv  = (long)4096 * 4096 / 4;   // 4,194,304

  if (ws_size >= (132ul << 20)) {
    // ---- Path A: fused QKV ----
    bf16* WqT  = (bf16*)(ws + (0l   << 20));  // 2 MB
    bf16* WkT  = (bf16*)(ws + (2l   << 20));  // 8 MB
    bf16* WvT  = (bf16*)(ws + (10l  << 20));  // 8 MB
    bf16* WoT  = (bf16*)(ws + (18l  << 20));  // 2 MB
    bf16* tgtb = (bf16*)(ws + (20l  << 20));  // 16 MB (attn out aliases later)
    bf16* srcb = (bf16*)(ws + (36l  << 20));  // 32 MB (vT aliases later)
    bf16* valb = (bf16*)(ws + (68l  << 20));  // 32 MB
    bf16* qb   = (bf16*)(ws + (100l << 20));  // 16 MB
    bf16* kb   = (bf16*)(ws + (116l << 20));  // 8 MB
    bf16* vb   = (bf16*)(ws + (124l << 20));  // 8 MB -> 132 MB total
    bf16* vTb   = srcb;  // srcb dead after QKV gemm
    bf16* attnb = tgtb;  // tgtb dead after QKV gemm

    transpose_cvt_w<<<10240, 256, 0, stream>>>(Wq, WqT, Wk, WkT, Wv, WvT, Wo, WoT);
    cvt3<<<4096, 256, 0, stream>>>(tgt, tgtb, n4_tgt, src, srcb, n4_sv, val, valb, n4_sv);
    gemm_qkv<<<1024, 256, 0, stream>>>(tgtb, WqT, bq, qb, 1024, 512,
                                       srcb, WkT, bk, kb, 4096, 256,
                                       valb, WvT, bv, vb, 4096);
    transpose_bf16_batched<<<dim3(32, 32, 4), 256, 0, stream>>>(vb, vTb, 1024, 1024);
    attn_fused<<<dim3(32, 64), 256, 0, stream>>>(qb, kb, vTb, attnb);
    gemm_bt<<<dim3(8, 64), 256, 0, stream>>>(attnb, WoT, bo, (bf16*)nullptr, out, 1024, 1024);
  } else {
    if (ws_size < (100ul << 20)) return;
    // ---- Path B: serialized (round-0 layout) ----
    bf16* WqT  = (bf16*)(ws + (0l  << 20));
    bf16* WkT  = (bf16*)(ws + (2l  << 20));
    bf16* WvT  = (bf16*)(ws + (10l << 20));
    bf16* WoT  = (bf16*)(ws + (18l << 20));
    bf16* tgtb = (bf16*)(ws + (20l << 20));
    bf16* srcb = (bf16*)(ws + (36l << 20));
    bf16* qb   = (bf16*)(ws + (68l << 20));
    bf16* kb   = (bf16*)(ws + (84l << 20));
    bf16* vTb  = (bf16*)(ws + (92l << 20));
    bf16* vb = WkT;
    bf16* attnb = tgtb;

    transpose_cvt_w<<<10240, 256, 0, stream>>>(Wq, WqT, Wk, WkT, Wv, WvT, Wo, WoT);
    cvt3<<<4096, 256, 0, stream>>>(tgt, tgtb, n4_tgt, src, srcb, n4_sv,
                                   (const float*)nullptr, (bf16*)nullptr, 0);
    gemm_bt<<<dim3(8, 64), 256, 0, stream>>>(tgtb, WqT, bq, qb, (float*)nullptr, 1024, 1024);
    gemm_bt<<<dim3(8, 32), 256, 0, stream>>>(srcb, WkT, bk, kb, (float*)nullptr, 1024, 4096);
    cvt3<<<4096, 256, 0, stream>>>(val, srcb, n4_sv, (const float*)nullptr, (bf16*)nullptr, 0,
                                   (const float*)nullptr, (bf16*)nullptr, 0);
    gemm_bt<<<dim3(8, 32), 256, 0, stream>>>(srcb, WvT, bv, vb, (float*)nullptr, 1024, 4096);
    transpose_bf16_batched<<<dim3(32, 32, 4), 256, 0, stream>>>(vb, vTb, 1024, 1024);
    attn_fused<<<dim3(32, 64), 256, 0, stream>>>(qb, kb, vTb, attnb);
    gemm_bt<<<dim3(8, 64), 256, 0, stream>>>(attnb, WoT, bo, (bf16*)nullptr, out, 1024, 1024);
  }
}

// Round 3
// 268.588 us; speedup vs baseline: 1.4563x; 1.0225x over previous
//
#include <hip/hip_runtime.h>
#include <hip/hip_bf16.h>

using bf16 = __hip_bfloat16;
typedef __attribute__((ext_vector_type(8))) short short8;
typedef __attribute__((ext_vector_type(4))) float f32x4;

static constexpr int Bc = 4, Lc = 2048, Sc = 1024;
static constexpr int DModel = 1024;

__device__ __forceinline__ void gload16(const void* g, void* l) {
  __builtin_amdgcn_global_load_lds((const __attribute__((address_space(1))) void*)g,
                                   (__attribute__((address_space(3))) void*)l,
                                   16, 0, 0);
}

// ---------------- fused conversions ----------------
__global__ void cvt3(const float* __restrict__ a, bf16* __restrict__ ao, long na4,
                     const float* __restrict__ b, bf16* __restrict__ bo, long nb4,
                     const float* __restrict__ c, bf16* __restrict__ co, long nc4) {
  long total = na4 + nb4 + nc4;
  long stride = (long)gridDim.x * blockDim.x;
  for (long i = (long)blockIdx.x * blockDim.x + threadIdx.x; i < total; i += stride) {
    const float* src; bf16* dst; long j;
    if (i < na4)            { src = a; dst = ao; j = i; }
    else if (i < na4 + nb4) { src = b; dst = bo; j = i - na4; }
    else                    { src = c; dst = co; j = i - na4 - nb4; }
    float4 v = reinterpret_cast<const float4*>(src)[j];
    alignas(8) bf16 t[4] = {__float2bfloat16(v.x), __float2bfloat16(v.y),
                            __float2bfloat16(v.z), __float2bfloat16(v.w)};
    reinterpret_cast<ushort4*>(dst)[j] = *reinterpret_cast<const ushort4*>(t);
  }
}

// all four weight transposes (f32 [R][C] -> bf16 [C][R]) in one launch
__global__ __launch_bounds__(256) void transpose_cvt_w(const float* __restrict__ Wq, bf16* __restrict__ WqT,
                                                       const float* __restrict__ Wk, bf16* __restrict__ WkT,
                                                       const float* __restrict__ Wv, bf16* __restrict__ WvT,
                                                       const float* __restrict__ Wo, bf16* __restrict__ WoT) {
  __shared__ bf16 tile[32][33];
  int bid = blockIdx.x;
  const float* in; bf16* out; int R, l;
  if (bid < 1024)      { in = Wq; out = WqT; R = 1024; l = bid; }
  else if (bid < 5120) { in = Wk; out = WkT; R = 4096; l = bid - 1024; }
  else if (bid < 9216) { in = Wv; out = WvT; R = 4096; l = bid - 5120; }
  else                 { in = Wo; out = WoT; R = 1024; l = bid - 9216; }
  const int C = 1024;
  int bx = l & 31, by = l >> 5;
  int tx = threadIdx.x & 31, ty = threadIdx.x >> 5;
  int r0 = by * 32, c0 = bx * 32;
#pragma unroll
  for (int i = 0; i < 32; i += 8)
    tile[ty + i][tx] = __float2bfloat16(in[(long)(r0 + ty + i) * C + c0 + tx]);
  __syncthreads();
#pragma unroll
  for (int i = 0; i < 32; i += 8)
    out[(long)(c0 + ty + i) * R + r0 + tx] = tile[tx][ty + i];
}

// ---------------- GEMM core (2-phase double-buffered) ----------------
// C[128x128 tile] = A[M][K] * Bt[N][K]^T + bias.
// LDS tiles XOR-swizzled via source-side pre-swizzle; global_load_lds linear dest.
// K-loop: stage tile t+1 (other buffer) BEFORE computing tile t; single
// __syncthreads per tile at the end (its vmcnt(0) drain overlaps with compute).
// Output modes: Cb (bf16 row-major), Cf (f32 row-major), Cvt (bf16 per-batch
// transposed [b][n][s] for the V projection).
__device__ __forceinline__ void gemm_core(const bf16* __restrict__ A, const bf16* __restrict__ Bt,
                                          const float* __restrict__ bias,
                                          bf16* __restrict__ Cb, float* __restrict__ Cf,
                                          bf16* __restrict__ Cvt,
                                          int N, int K, int bx, int by,
                                          bf16* As, bf16* Bs) {
  const int tid = threadIdx.x;
  const int lane = tid & 63, g = lane >> 4, lm = lane & 15;
  const int wid = tid >> 6, wr = wid >> 1, wc = wid & 1;
  const long brow = (long)by * 128, bcol = (long)bx * 128;

  // per-thread staging addresses (4 slots of 16B per matrix)
  const bf16* asrc[4];
  const bf16* bsrc[4];
  int dsto[4];
#pragma unroll
  for (int t = 0; t < 4; ++t) {
    int sl = tid + t * 256;
    int row = sl >> 3;
    int kg = (sl & 7) ^ (row & 7);  // source pre-swizzle
    asrc[t] = A + (brow + row) * (long)K + kg * 8;
    bsrc[t] = Bt + (bcol + row) * (long)K + kg * 8;
    dsto[t] = sl * 16;
  }

  f32x4 zero = {0.f, 0.f, 0.f, 0.f};
  f32x4 acc[4][4];
#pragma unroll
  for (int i = 0; i < 4; ++i)
#pragma unroll
    for (int j = 0; j < 4; ++j) acc[i][j] = zero;

  char* Asc = (char*)As;
  char* Bsc = (char*)Bs;

  // prologue: stage tile 0 into buffer 0
#pragma unroll
  for (int t = 0; t < 4; ++t) {
    gload16(asrc[t], Asc + dsto[t]);
    gload16(bsrc[t], Bsc + dsto[t]);
    asrc[t] += 64; bsrc[t] += 64;
  }
  __syncthreads();

  const int nt = K >> 6;
  for (int i = 0; i < nt; ++i) {
    const int cur = i & 1;
    if (i + 1 < nt) {
      const int nxt = cur ^ 1;
#pragma unroll
      for (int t = 0; t < 4; ++t) {
        gload16(asrc[t], Asc + nxt * 16384 + dsto[t]);
        gload16(bsrc[t], Bsc + nxt * 16384 + dsto[t]);
        asrc[t] += 64; bsrc[t] += 64;
      }
    }
    const char* Ab = Asc + cur * 16384;
    const char* Bb = Bsc + cur * 16384;
    __builtin_amdgcn_s_setprio(1);
#pragma unroll
    for (int ks = 0; ks < 2; ++ks) {
      short8 af[4], bfv[4];
#pragma unroll
      for (int mi = 0; mi < 4; ++mi) {
        int m = wr * 64 + mi * 16 + lm;
        af[mi] = *reinterpret_cast<const short8*>(
            Ab + ((m * 128 + ks * 64 + g * 16) ^ ((m & 7) << 4)));
      }
#pragma unroll
      for (int ni = 0; ni < 4; ++ni) {
        int n = wc * 64 + ni * 16 + lm;
        bfv[ni] = *reinterpret_cast<const short8*>(
            Bb + ((n * 128 + ks * 64 + g * 16) ^ ((n & 7) << 4)));
      }
#pragma unroll
      for (int mi = 0; mi < 4; ++mi)
#pragma unroll
        for (int ni = 0; ni < 4; ++ni)
          acc[mi][ni] = __builtin_amdgcn_mfma_f32_16x16x32_bf16(af[mi], bfv[ni], acc[mi][ni], 0, 0, 0);
    }
    __builtin_amdgcn_s_setprio(0);
    __syncthreads();  // drains vmcnt(0): tile i+1 landed; readers of buf cur done
  }

  // epilogue: D layout col = lane&15, row = (lane>>4)*4 + r
#pragma unroll
  for (int ni = 0; ni < 4; ++ni) {
    long n = bcol + wc * 64 + ni * 16 + lm;
    float bv = bias ? bias[n] : 0.f;
#pragma unroll
    for (int mi = 0; mi < 4; ++mi) {
      long m0 = brow + wr * 64 + mi * 16 + g * 4;
      if (Cvt) {
        // per-batch transposed write: [b][n][s], 4 consecutive s per lane
        long b = m0 >> 10, s0 = m0 & 1023;
        alignas(8) bf16 t4[4];
#pragma unroll
        for (int r = 0; r < 4; ++r) t4[r] = __float2bfloat16(acc[mi][ni][r] + bv);
        *reinterpret_cast<ushort4*>(Cvt + ((b << 10) + n) * 1024 + s0) =
            *reinterpret_cast<const ushort4*>(t4);
      } else {
#pragma unroll
        for (int r = 0; r < 4; ++r) {
          float o = acc[mi][ni][r] + bv;
          if (Cb) Cb[(m0 + r) * N + n] = __float2bfloat16(o);
          else    Cf[(m0 + r) * N + n] = o;
        }
      }
    }
  }
}

__global__ __launch_bounds__(256) void gemm_bt(const bf16* __restrict__ A,
                                               const bf16* __restrict__ Bt,
                                               const float* __restrict__ bias,
                                               bf16* __restrict__ Cb,
                                               float* __restrict__ Cf,
                                               int N, int K) {
  __shared__ bf16 As[2 * 128 * 64];
  __shared__ bf16 Bs[2 * 128 * 64];
  gemm_core(A, Bt, bias, Cb, Cf, nullptr, N, K, blockIdx.x, blockIdx.y, As, Bs);
}

// Q/K/V projections fused; heavy K=4096 segments (K,V) dispatch first.
// V segment writes vT [b][n][s] directly (outmode Cvt).
__global__ __launch_bounds__(256) void gemm_qkv(
    const bf16* __restrict__ Ak, const bf16* __restrict__ Bk, const float* __restrict__ bk_, bf16* __restrict__ Ck, int Kk, int nbk,
    const bf16* __restrict__ Av, const bf16* __restrict__ Bv_, const float* __restrict__ bv_, bf16* __restrict__ CvT, int Kv, int nbv,
    const bf16* __restrict__ Aq, const bf16* __restrict__ Bq_, const float* __restrict__ bq_, bf16* __restrict__ Cq, int Kq) {
  __shared__ bf16 As[2 * 128 * 64];
  __shared__ bf16 Bs[2 * 128 * 64];
  int bid = blockIdx.x;
  const bf16 *A, *Bt; const float* bias; bf16 *C = nullptr, *Cvt = nullptr; int K, l;
  if (bid < nbk)            { A = Ak; Bt = Bk;  bias = bk_; C = Ck;    K = Kk; l = bid; }
  else if (bid < nbk + nbv) { A = Av; Bt = Bv_; bias = bv_; Cvt = CvT; K = Kv; l = bid - nbk; }
  else                      { A = Aq; Bt = Bq_; bias = bq_; C = Cq;   K = Kq; l = bid - nbk - nbv; }
  gemm_core(A, Bt, bias, C, nullptr, Cvt, 1024, K, l & 7, l >> 3, As, Bs);
}

// ---------------- fused flash attention (2-phase K/V staging) ----------------
// One block = one (b,h), 64 q rows. 4 waves x 16 q rows each.
// Q pre-scaled by C2 = (1/8)*log2(e); row-sum via MFMA ones-fragment; defer-max.
__global__ __launch_bounds__(256) void attn_fused(const bf16* __restrict__ q,
                                                  const bf16* __restrict__ k,
                                                  const bf16* __restrict__ vT,
                                                  bf16* __restrict__ o) {
  constexpr float C2 = 0.18033688011112042f;  // (1/8) * log2(e)
  constexpr float THR = 6.0f;
  __shared__ bf16 Kl[2][64 * 64];   // [s][e], swizzled, double-buffered
  __shared__ bf16 Vl[2][64 * 64];   // [e][s], swizzled, double-buffered
  __shared__ bf16 Pl[4][16 * 64];   // per-wave [q][s], swizzled
  const int tid = threadIdx.x;
  const int lane = tid & 63, g = lane >> 4, lm = lane & 15;
  const int wid = tid >> 6;
  const int b = blockIdx.y >> 4, h = blockIdx.y & 15;
  const int qbase = blockIdx.x * 64 + wid * 16;

  const bf16* qrow = q + (long)(b * Lc + qbase + lm) * DModel + h * 64;
  short8 qa0 = *reinterpret_cast<const short8*>(qrow + g * 8);
  short8 qa1 = *reinterpret_cast<const short8*>(qrow + 32 + g * 8);
#pragma unroll
  for (int j = 0; j < 8; ++j) {
    union { ushort u; bf16 h; } cv;
    cv.u = (ushort)qa0[j];
    bf16 s0 = __float2bfloat16(__bfloat162float(cv.h) * C2);
    qa0[j] = (short)*reinterpret_cast<ushort*>(&s0);
    cv.u = (ushort)qa1[j];
    bf16 s1 = __float2bfloat16(__bfloat162float(cv.h) * C2);
    qa1[j] = (short)*reinterpret_cast<ushort*>(&s1);
  }

  const bf16* kbase = k + (long)b * Sc * DModel + h * 64;
  const bf16* vbase = vT + ((long)b * DModel + h * 64) * Sc;

  // staging addresses: 2 slots of 16B per matrix per thread
  const bf16* ksrc[2];
  const bf16* vsrc[2];
  int dsto[2];
#pragma unroll
  for (int t = 0; t < 2; ++t) {
    int sl = tid + t * 256;
    int row = sl >> 3;
    int cg = (sl & 7) ^ (row & 7);
    ksrc[t] = kbase + (long)row * DModel + cg * 8;  // advances 64*DModel per tile
    vsrc[t] = vbase + (long)row * Sc + cg * 8;      // advances 64 per tile
    dsto[t] = sl * 16;
  }

  f32x4 zero = {0.f, 0.f, 0.f, 0.f};
  f32x4 accO[4];
#pragma unroll
  for (int i = 0; i < 4; ++i) accO[i] = zero;
  f32x4 accL = zero;
  float mst[4] = {-1e30f, -1e30f, -1e30f, -1e30f};

  short8 vones;
#pragma unroll
  for (int j = 0; j < 8; ++j) vones[j] = (short)0x3F80;  // bf16 1.0

  char* Klc = (char*)Kl;
  char* Vlc = (char*)Vl;
  char* Plc = (char*)Pl + wid * (16 * 64 * 2);

  // prologue: stage tile 0 into buffer 0
#pragma unroll
  for (int t = 0; t < 2; ++t) {
    gload16(ksrc[t], Klc + dsto[t]);
    gload16(vsrc[t], Vlc + dsto[t]);
    ksrc[t] += 64 * DModel; vsrc[t] += 64;
  }
  __syncthreads();

  for (int j = 0; j < Sc / 64; ++j) {
    const int cur = j & 1;
    if (j + 1 < Sc / 64) {
      const int nxt = cur ^ 1;
#pragma unroll
      for (int t = 0; t < 2; ++t) {
        gload16(ksrc[t], Klc + nxt * 8192 + dsto[t]);
        gload16(vsrc[t], Vlc + nxt * 8192 + dsto[t]);
        ksrc[t] += 64 * DModel; vsrc[t] += 64;
      }
    }
    const char* Kb = Klc + cur * 8192;
    const char* Vb = Vlc + cur * 8192;

    // QK^T (scaled): D rows = q (4g+r), cols = s (st*16+lm)
    f32x4 scv[4];
    __builtin_amdgcn_s_setprio(1);
#pragma unroll
    for (int st = 0; st < 4; ++st) {
      int s = st * 16 + lm;
      int sw = (s & 7) << 4;
      short8 kb0 = *reinterpret_cast<const short8*>(Kb + ((s * 128 + g * 16) ^ sw));
      short8 kb1 = *reinterpret_cast<const short8*>(Kb + ((s * 128 + 64 + g * 16) ^ sw));
      f32x4 z = zero;
      z = __builtin_amdgcn_mfma_f32_16x16x32_bf16(qa0, kb0, z, 0, 0, 0);
      z = __builtin_amdgcn_mfma_f32_16x16x32_bf16(qa1, kb1, z, 0, 0, 0);
      scv[st] = z;
    }
    __builtin_amdgcn_s_setprio(0);

    // online softmax with defer-max
    float pmax[4];
#pragma unroll
    for (int r = 0; r < 4; ++r)
      pmax[r] = fmaxf(fmaxf(scv[0][r], scv[1][r]), fmaxf(scv[2][r], scv[3][r]));
    int need = 0;
#pragma unroll
    for (int r = 0; r < 4; ++r) need |= (pmax[r] > mst[r] + THR) ? 1 : 0;
    if (__any(need)) {
#pragma unroll
      for (int r = 0; r < 4; ++r) {
        float mx = pmax[r];
        mx = fmaxf(mx, __shfl_xor(mx, 1));
        mx = fmaxf(mx, __shfl_xor(mx, 2));
        mx = fmaxf(mx, __shfl_xor(mx, 4));
        mx = fmaxf(mx, __shfl_xor(mx, 8));
        float mnew = fmaxf(mst[r], mx);
        float corr = __builtin_amdgcn_exp2f(mst[r] - mnew);
        mst[r] = mnew;
        accL[r] *= corr;
#pragma unroll
        for (int et = 0; et < 4; ++et) accO[et][r] *= corr;
      }
    }
#pragma unroll
    for (int r = 0; r < 4; ++r) {
      int qq = g * 4 + r;
      int swp = (qq & 7) << 4;
#pragma unroll
      for (int st = 0; st < 4; ++st) {
        float p = __builtin_amdgcn_exp2f(scv[st][r] - mst[r]);
        *reinterpret_cast<bf16*>(Plc + ((qq * 128 + (st * 16 + lm) * 2) ^ swp)) =
            __float2bfloat16(p);
      }
    }

    // PV: out[q][e] += P[q][s] * V[s][e]; l += P[q][s] * 1
    __builtin_amdgcn_s_setprio(1);
#pragma unroll
    for (int sk = 0; sk < 2; ++sk) {
      short8 pa = *reinterpret_cast<const short8*>(
          Plc + ((lm * 128 + sk * 64 + g * 16) ^ ((lm & 7) << 4)));
      accL = __builtin_amdgcn_mfma_f32_16x16x32_bf16(pa, vones, accL, 0, 0, 0);
#pragma unroll
      for (int et = 0; et < 4; ++et) {
        int e = et * 16 + lm;
        short8 vb = *reinterpret_cast<const short8*>(
            Vb + ((e * 128 + sk * 64 + g * 16) ^ ((e & 7) << 4)));
        accO[et] = __builtin_amdgcn_mfma_f32_16x16x32_bf16(pa, vb, accO[et], 0, 0, 0);
      }
    }
    __builtin_amdgcn_s_setprio(0);
    __syncthreads();  // drains vmcnt(0): tile j+1 landed; readers of buf cur done
  }

#pragma unroll
  for (int r = 0; r < 4; ++r) {
    float inv = 1.0f / accL[r];
    long row = (long)(b * Lc + qbase + g * 4 + r);
#pragma unroll
    for (int et = 0; et < 4; ++et)
      o[row * DModel + h * 64 + et * 16 + lm] = __float2bfloat16(accO[et][r] * inv);
  }
}

// ---------------- host launch ----------------
extern "C" void kernel_launch(void* const* d_in, const int* in_sizes, int n_in,
                              void* d_out, int out_size, void* d_ws, size_t ws_size,
                              hipStream_t stream) {
  const float* tgt = (const float*)d_in[0];
  const float* src = (const float*)d_in[1];
  const float* val = (const float*)d_in[2];
  const float* Wq  = (const float*)d_in[3];
  const float* bq  = (const float*)d_in[4];
  const float* Wk  = (const float*)d_in[5];
  const float* bk  = (const float*)d_in[6];
  const float* Wv  = (const float*)d_in[7];
  const float* bv  = (const float*)d_in[8];
  const float* Wo  = (const float*)d_in[9];
  const float* bo  = (const float*)d_in[10];
  float* out = (float*)d_out;
  char* ws = (char*)d_ws;

  const long n4_tgt = (long)8192 * 1024 / 4;
  const long n4_sv  = (long)4096 * 4096 / 4;

  if (ws_size < (132ul << 20)) return;

  bf16* WqT  = (bf16*)(ws + (0l   << 20));  // 2 MB
  bf16* WkT  = (bf16*)(ws + (2l   << 20));  // 8 MB
  bf16* WvT  = (bf16*)(ws + (10l  << 20));  // 8 MB
  bf16* WoT  = (bf16*)(ws + (18l  << 20));  // 2 MB
  bf16* tgtb = (bf16*)(ws + (20l  << 20));  // 16 MB (attn out aliases later)
  bf16* srcb = (bf16*)(ws + (36l  << 20));  // 32 MB
  bf16* valb = (bf16*)(ws + (68l  << 20));  // 32 MB
  bf16* qb   = (bf16*)(ws + (100l << 20));  // 16 MB
  bf16* kb   = (bf16*)(ws + (116l << 20));  // 8 MB
  bf16* vTb  = (bf16*)(ws + (124l << 20));  // 8 MB [4][1024][1024] -> 132 MB
  bf16* attnb = tgtb;  // tgtb dead after QKV gemm

  transpose_cvt_w<<<10240, 256, 0, stream>>>(Wq, WqT, Wk, WkT, Wv, WvT, Wo, WoT);
  cvt3<<<4096, 256, 0, stream>>>(tgt, tgtb, n4_tgt, src, srcb, n4_sv, val, valb, n4_sv);
  // segments: K-proj (256 blocks), V-proj->vT (256), Q-proj (512)
  gemm_qkv<<<1024, 256, 0, stream>>>(srcb, WkT, bk, kb, 4096, 256,
                                     valb, WvT, bv, vTb, 4096, 256,
                                     tgtb, WqT, bq, qb, 1024);
  attn_fused<<<dim3(32, 64), 256, 0, stream>>>(qb, kb, vTb, attnb);
  gemm_bt<<<dim3(8, 64), 256, 0, stream>>>(attnb, WoT, bo, (bf16*)nullptr, out, 1024, 1024);
}

// Round 4
// 252.532 us; speedup vs baseline: 1.5489x; 1.0636x over previous
//
#include <hip/hip_runtime.h>
#include <hip/hip_bf16.h>

using bf16 = __hip_bfloat16;
typedef __attribute__((ext_vector_type(8))) short short8;
typedef __attribute__((ext_vector_type(4))) float f32x4;

static constexpr int Bc = 4, Lc = 2048, Sc = 1024;
static constexpr int DModel = 1024;

__device__ __forceinline__ void gload16(const void* g, void* l) {
  __builtin_amdgcn_global_load_lds((const __attribute__((address_space(1))) void*)g,
                                   (__attribute__((address_space(3))) void*)l,
                                   16, 0, 0);
}

__device__ __forceinline__ void wait_vm8()  { asm volatile("s_waitcnt vmcnt(8)" ::: "memory"); }
__device__ __forceinline__ void wait_vm4()  { asm volatile("s_waitcnt vmcnt(4)" ::: "memory"); }
__device__ __forceinline__ void wait_vm0()  { asm volatile("s_waitcnt vmcnt(0)" ::: "memory"); }
__device__ __forceinline__ void barrier_raw() { asm volatile("s_barrier" ::: "memory"); }

// ---------------- fused conversions ----------------
__global__ void cvt3(const float* __restrict__ a, bf16* __restrict__ ao, long na4,
                     const float* __restrict__ b, bf16* __restrict__ bo, long nb4,
                     const float* __restrict__ c, bf16* __restrict__ co, long nc4) {
  long total = na4 + nb4 + nc4;
  long stride = (long)gridDim.x * blockDim.x;
  for (long i = (long)blockIdx.x * blockDim.x + threadIdx.x; i < total; i += stride) {
    const float* src; bf16* dst; long j;
    if (i < na4)            { src = a; dst = ao; j = i; }
    else if (i < na4 + nb4) { src = b; dst = bo; j = i - na4; }
    else                    { src = c; dst = co; j = i - na4 - nb4; }
    float4 v = reinterpret_cast<const float4*>(src)[j];
    alignas(8) bf16 t[4] = {__float2bfloat16(v.x), __float2bfloat16(v.y),
                            __float2bfloat16(v.z), __float2bfloat16(v.w)};
    reinterpret_cast<ushort4*>(dst)[j] = *reinterpret_cast<const ushort4*>(t);
  }
}

// all four weight transposes (f32 [R][C] -> bf16 [C][R]) in one launch
__global__ __launch_bounds__(256) void transpose_cvt_w(const float* __restrict__ Wq, bf16* __restrict__ WqT,
                                                       const float* __restrict__ Wk, bf16* __restrict__ WkT,
                                                       const float* __restrict__ Wv, bf16* __restrict__ WvT,
                                                       const float* __restrict__ Wo, bf16* __restrict__ WoT) {
  __shared__ bf16 tile[32][33];
  int bid = blockIdx.x;
  const float* in; bf16* out; int R, l;
  if (bid < 1024)      { in = Wq; out = WqT; R = 1024; l = bid; }
  else if (bid < 5120) { in = Wk; out = WkT; R = 4096; l = bid - 1024; }
  else if (bid < 9216) { in = Wv; out = WvT; R = 4096; l = bid - 5120; }
  else                 { in = Wo; out = WoT; R = 1024; l = bid - 9216; }
  const int C = 1024;
  int bx = l & 31, by = l >> 5;
  int tx = threadIdx.x & 31, ty = threadIdx.x >> 5;
  int r0 = by * 32, c0 = bx * 32;
#pragma unroll
  for (int i = 0; i < 32; i += 8)
    tile[ty + i][tx] = __float2bfloat16(in[(long)(r0 + ty + i) * C + c0 + tx]);
  __syncthreads();
#pragma unroll
  for (int i = 0; i < 32; i += 8)
    out[(long)(c0 + ty + i) * R + r0 + tx] = tile[tx][ty + i];
}

// ---------------- GEMM core (2-phase dbuf, counted vmcnt) ----------------
// C[128x128 tile] = A[M][K] * Bt[N][K]^T + bias.
// LDS XOR-swizzled via source-side pre-swizzle; global_load_lds linear dest.
// Loop: {stage next tile (8 loads); vmcnt(8); barrier; compute; barrier}.
// vmcnt(8) waits only on the PREVIOUS iteration's loads (full iter of cover);
// never drains the just-issued 8. No other VMEM ops inside the loop.
__device__ __forceinline__ void gemm_core(const bf16* __restrict__ A, const bf16* __restrict__ Bt,
                                          const float* __restrict__ bias,
                                          bf16* __restrict__ Cb, float* __restrict__ Cf,
                                          bf16* __restrict__ Cvt,
                                          int N, int K, int bx, int by,
                                          bf16* As, bf16* Bs) {
  const int tid = threadIdx.x;
  const int lane = tid & 63, g = lane >> 4, lm = lane & 15;
  const int wid = tid >> 6, wr = wid >> 1, wc = wid & 1;
  const long brow = (long)by * 128, bcol = (long)bx * 128;

  const bf16* asrc[4];
  const bf16* bsrc[4];
  int dsto[4];
#pragma unroll
  for (int t = 0; t < 4; ++t) {
    int sl = tid + t * 256;
    int row = sl >> 3;
    int kg = (sl & 7) ^ (row & 7);  // source pre-swizzle
    asrc[t] = A + (brow + row) * (long)K + kg * 8;
    bsrc[t] = Bt + (bcol + row) * (long)K + kg * 8;
    dsto[t] = sl * 16;
  }

  f32x4 zero = {0.f, 0.f, 0.f, 0.f};
  f32x4 acc[4][4];
#pragma unroll
  for (int i = 0; i < 4; ++i)
#pragma unroll
    for (int j = 0; j < 4; ++j) acc[i][j] = zero;

  char* Asc = (char*)As;
  char* Bsc = (char*)Bs;

  // prologue: stage tile 0 into buffer 0
#pragma unroll
  for (int t = 0; t < 4; ++t) {
    gload16(asrc[t], Asc + dsto[t]);
    gload16(bsrc[t], Bsc + dsto[t]);
    asrc[t] += 64; bsrc[t] += 64;
  }

  const int nt = K >> 6;
  for (int i = 0; i < nt; ++i) {
    const int cur = i & 1;
    if (i + 1 < nt) {
      const int nxt = cur ^ 1;
#pragma unroll
      for (int t = 0; t < 4; ++t) {
        gload16(asrc[t], Asc + nxt * 16384 + dsto[t]);
        gload16(bsrc[t], Bsc + nxt * 16384 + dsto[t]);
        asrc[t] += 64; bsrc[t] += 64;
      }
      wait_vm8();   // tile i's 8 loads landed (issued one full iter ago)
    } else {
      wait_vm0();
    }
    barrier_raw();  // all waves' tile-i loads landed; WAR for buf[nxt] already held

    const char* Ab = Asc + cur * 16384;
    const char* Bb = Bsc + cur * 16384;
    __builtin_amdgcn_s_setprio(1);
#pragma unroll
    for (int ks = 0; ks < 2; ++ks) {
      short8 af[4], bfv[4];
#pragma unroll
      for (int mi = 0; mi < 4; ++mi) {
        int m = wr * 64 + mi * 16 + lm;
        af[mi] = *reinterpret_cast<const short8*>(
            Ab + ((m * 128 + ks * 64 + g * 16) ^ ((m & 7) << 4)));
      }
#pragma unroll
      for (int ni = 0; ni < 4; ++ni) {
        int n = wc * 64 + ni * 16 + lm;
        bfv[ni] = *reinterpret_cast<const short8*>(
            Bb + ((n * 128 + ks * 64 + g * 16) ^ ((n & 7) << 4)));
      }
#pragma unroll
      for (int mi = 0; mi < 4; ++mi)
#pragma unroll
        for (int ni = 0; ni < 4; ++ni)
          acc[mi][ni] = __builtin_amdgcn_mfma_f32_16x16x32_bf16(af[mi], bfv[ni], acc[mi][ni], 0, 0, 0);
    }
    __builtin_amdgcn_s_setprio(0);
    barrier_raw();  // all waves done reading buf[cur] -> safe to overwrite next iter
  }

  // epilogue: D layout col = lane&15, row = (lane>>4)*4 + r
#pragma unroll
  for (int ni = 0; ni < 4; ++ni) {
    long n = bcol + wc * 64 + ni * 16 + lm;
    float bv = bias ? bias[n] : 0.f;
#pragma unroll
    for (int mi = 0; mi < 4; ++mi) {
      long m0 = brow + wr * 64 + mi * 16 + g * 4;
      if (Cvt) {
        long b = m0 >> 10, s0 = m0 & 1023;
        alignas(8) bf16 t4[4];
#pragma unroll
        for (int r = 0; r < 4; ++r) t4[r] = __float2bfloat16(acc[mi][ni][r] + bv);
        *reinterpret_cast<ushort4*>(Cvt + ((b << 10) + n) * 1024 + s0) =
            *reinterpret_cast<const ushort4*>(t4);
      } else {
#pragma unroll
        for (int r = 0; r < 4; ++r) {
          float o = acc[mi][ni][r] + bv;
          if (Cb) Cb[(m0 + r) * N + n] = __float2bfloat16(o);
          else    Cf[(m0 + r) * N + n] = o;
        }
      }
    }
  }
}

// O-proj GEMM, 1D grid (512), XCD-swizzled: per-XCD contiguous by-panels.
__global__ __launch_bounds__(256) void gemm_bt(const bf16* __restrict__ A,
                                               const bf16* __restrict__ Bt,
                                               const float* __restrict__ bias,
                                               bf16* __restrict__ Cb,
                                               float* __restrict__ Cf,
                                               int N, int K) {
  __shared__ bf16 As[2 * 128 * 64];
  __shared__ bf16 Bs[2 * 128 * 64];
  int bid = blockIdx.x;
  int g = (bid & 7) * (gridDim.x >> 3) + (bid >> 3);  // XCD-contiguous logical id
  gemm_core(A, Bt, bias, Cb, Cf, nullptr, N, K, g & 7, g >> 3, As, Bs);
}

// Q/K/V projections fused; heavy K=4096 segments first; per-segment XCD swizzle.
__global__ __launch_bounds__(256) void gemm_qkv(
    const bf16* __restrict__ Ak, const bf16* __restrict__ Bk, const float* __restrict__ bk_, bf16* __restrict__ Ck, int Kk, int nbk,
    const bf16* __restrict__ Av, const bf16* __restrict__ Bv_, const float* __restrict__ bv_, bf16* __restrict__ CvT, int Kv, int nbv,
    const bf16* __restrict__ Aq, const bf16* __restrict__ Bq_, const float* __restrict__ bq_, bf16* __restrict__ Cq, int Kq) {
  __shared__ bf16 As[2 * 128 * 64];
  __shared__ bf16 Bs[2 * 128 * 64];
  int bid = blockIdx.x;
  const bf16 *A, *Bt; const float* bias; bf16 *C = nullptr, *Cvt = nullptr; int K, l, nb;
  if (bid < nbk)            { A = Ak; Bt = Bk;  bias = bk_; C = Ck;    K = Kk; l = bid;             nb = nbk; }
  else if (bid < nbk + nbv) { A = Av; Bt = Bv_; bias = bv_; Cvt = CvT; K = Kv; l = bid - nbk;       nb = nbv; }
  else                      { A = Aq; Bt = Bq_; bias = bq_; C = Cq;   K = Kq; l = bid - nbk - nbv; nb = gridDim.x - nbk - nbv; }
  // segment offsets are multiples of 8, so (l & 7) is still the XCD id.
  int g = (l & 7) * (nb >> 3) + (l >> 3);
  gemm_core(A, Bt, bias, C, nullptr, Cvt, 1024, K, g & 7, g >> 3, As, Bs);
}

// ---------------- fused flash attention (2-phase, counted vmcnt, XCD swizzle) ----
// 1D grid 2048; one block = one (b,h) x 64 q rows; 4 waves x 16 q rows.
__global__ __launch_bounds__(256) void attn_fused(const bf16* __restrict__ q,
                                                  const bf16* __restrict__ k,
                                                  const bf16* __restrict__ vT,
                                                  bf16* __restrict__ o) {
  constexpr float C2 = 0.18033688011112042f;  // (1/8) * log2(e)
  constexpr float THR = 6.0f;
  __shared__ bf16 Kl[2][64 * 64];
  __shared__ bf16 Vl[2][64 * 64];
  __shared__ bf16 Pl[4][16 * 64];
  const int tid = threadIdx.x;
  const int lane = tid & 63, g = lane >> 4, lm = lane & 15;
  const int wid = tid >> 6;
  int bid = blockIdx.x;
  int gl = (bid & 7) * 256 + (bid >> 3);  // per-XCD contiguous: 8 bh x 32 qtiles
  const int qt = gl & 31, bh = gl >> 5;
  const int b = bh >> 4, h = bh & 15;
  const int qbase = qt * 64 + wid * 16;

  const bf16* qrow = q + (long)(b * Lc + qbase + lm) * DModel + h * 64;
  short8 qa0 = *reinterpret_cast<const short8*>(qrow + g * 8);
  short8 qa1 = *reinterpret_cast<const short8*>(qrow + 32 + g * 8);
#pragma unroll
  for (int j = 0; j < 8; ++j) {
    union { ushort u; bf16 h; } cv;
    cv.u = (ushort)qa0[j];
    bf16 s0 = __float2bfloat16(__bfloat162float(cv.h) * C2);
    qa0[j] = (short)*reinterpret_cast<ushort*>(&s0);
    cv.u = (ushort)qa1[j];
    bf16 s1 = __float2bfloat16(__bfloat162float(cv.h) * C2);
    qa1[j] = (short)*reinterpret_cast<ushort*>(&s1);
  }

  const bf16* kbase = k + (long)b * Sc * DModel + h * 64;
  const bf16* vbase = vT + ((long)b * DModel + h * 64) * Sc;

  const bf16* ksrc[2];
  const bf16* vsrc[2];
  int dsto[2];
#pragma unroll
  for (int t = 0; t < 2; ++t) {
    int sl = tid + t * 256;
    int row = sl >> 3;
    int cg = (sl & 7) ^ (row & 7);
    ksrc[t] = kbase + (long)row * DModel + cg * 8;
    vsrc[t] = vbase + (long)row * Sc + cg * 8;
    dsto[t] = sl * 16;
  }

  f32x4 zero = {0.f, 0.f, 0.f, 0.f};
  f32x4 accO[4];
#pragma unroll
  for (int i = 0; i < 4; ++i) accO[i] = zero;
  f32x4 accL = zero;
  float mst[4] = {-1e30f, -1e30f, -1e30f, -1e30f};

  short8 vones;
#pragma unroll
  for (int j = 0; j < 8; ++j) vones[j] = (short)0x3F80;  // bf16 1.0

  char* Klc = (char*)Kl;
  char* Vlc = (char*)Vl;
  char* Plc = (char*)Pl + wid * (16 * 64 * 2);

  // prologue: stage tile 0 into buffer 0
#pragma unroll
  for (int t = 0; t < 2; ++t) {
    gload16(ksrc[t], Klc + dsto[t]);
    gload16(vsrc[t], Vlc + dsto[t]);
    ksrc[t] += 64 * DModel; vsrc[t] += 64;
  }

  for (int j = 0; j < Sc / 64; ++j) {
    const int cur = j & 1;
    if (j + 1 < Sc / 64) {
      const int nxt = cur ^ 1;
#pragma unroll
      for (int t = 0; t < 2; ++t) {
        gload16(ksrc[t], Klc + nxt * 8192 + dsto[t]);
        gload16(vsrc[t], Vlc + nxt * 8192 + dsto[t]);
        ksrc[t] += 64 * DModel; vsrc[t] += 64;
      }
      wait_vm4();   // tile j's 4 loads landed
    } else {
      wait_vm0();
    }
    barrier_raw();

    const char* Kb = Klc + cur * 8192;
    const char* Vb = Vlc + cur * 8192;

    f32x4 scv[4];
    __builtin_amdgcn_s_setprio(1);
#pragma unroll
    for (int st = 0; st < 4; ++st) {
      int s = st * 16 + lm;
      int sw = (s & 7) << 4;
      short8 kb0 = *reinterpret_cast<const short8*>(Kb + ((s * 128 + g * 16) ^ sw));
      short8 kb1 = *reinterpret_cast<const short8*>(Kb + ((s * 128 + 64 + g * 16) ^ sw));
      f32x4 z = zero;
      z = __builtin_amdgcn_mfma_f32_16x16x32_bf16(qa0, kb0, z, 0, 0, 0);
      z = __builtin_amdgcn_mfma_f32_16x16x32_bf16(qa1, kb1, z, 0, 0, 0);
      scv[st] = z;
    }
    __builtin_amdgcn_s_setprio(0);

    float pmax[4];
#pragma unroll
    for (int r = 0; r < 4; ++r)
      pmax[r] = fmaxf(fmaxf(scv[0][r], scv[1][r]), fmaxf(scv[2][r], scv[3][r]));
    int need = 0;
#pragma unroll
    for (int r = 0; r < 4; ++r) need |= (pmax[r] > mst[r] + THR) ? 1 : 0;
    if (__any(need)) {
#pragma unroll
      for (int r = 0; r < 4; ++r) {
        float mx = pmax[r];
        mx = fmaxf(mx, __shfl_xor(mx, 1));
        mx = fmaxf(mx, __shfl_xor(mx, 2));
        mx = fmaxf(mx, __shfl_xor(mx, 4));
        mx = fmaxf(mx, __shfl_xor(mx, 8));
        float mnew = fmaxf(mst[r], mx);
        float corr = __builtin_amdgcn_exp2f(mst[r] - mnew);
        mst[r] = mnew;
        accL[r] *= corr;
#pragma unroll
        for (int et = 0; et < 4; ++et) accO[et][r] *= corr;
      }
    }
#pragma unroll
    for (int r = 0; r < 4; ++r) {
      int qq = g * 4 + r;
      int swp = (qq & 7) << 4;
#pragma unroll
      for (int st = 0; st < 4; ++st) {
        float p = __builtin_amdgcn_exp2f(scv[st][r] - mst[r]);
        *reinterpret_cast<bf16*>(Plc + ((qq * 128 + (st * 16 + lm) * 2) ^ swp)) =
            __float2bfloat16(p);
      }
    }

    __builtin_amdgcn_s_setprio(1);
#pragma unroll
    for (int sk = 0; sk < 2; ++sk) {
      short8 pa = *reinterpret_cast<const short8*>(
          Plc + ((lm * 128 + sk * 64 + g * 16) ^ ((lm & 7) << 4)));
      accL = __builtin_amdgcn_mfma_f32_16x16x32_bf16(pa, vones, accL, 0, 0, 0);
#pragma unroll
      for (int et = 0; et < 4; ++et) {
        int e = et * 16 + lm;
        short8 vb = *reinterpret_cast<const short8*>(
            Vb + ((e * 128 + sk * 64 + g * 16) ^ ((e & 7) << 4)));
        accO[et] = __builtin_amdgcn_mfma_f32_16x16x32_bf16(pa, vb, accO[et], 0, 0, 0);
      }
    }
    __builtin_amdgcn_s_setprio(0);
    barrier_raw();
  }

#pragma unroll
  for (int r = 0; r < 4; ++r) {
    float inv = 1.0f / accL[r];
    long row = (long)(b * Lc + qbase + g * 4 + r);
#pragma unroll
    for (int et = 0; et < 4; ++et)
      o[row * DModel + h * 64 + et * 16 + lm] = __float2bfloat16(accO[et][r] * inv);
  }
}

// ---------------- host launch ----------------
extern "C" void kernel_launch(void* const* d_in, const int* in_sizes, int n_in,
                              void* d_out, int out_size, void* d_ws, size_t ws_size,
                              hipStream_t stream) {
  const float* tgt = (const float*)d_in[0];
  const float* src = (const float*)d_in[1];
  const float* val = (const float*)d_in[2];
  const float* Wq  = (const float*)d_in[3];
  const float* bq  = (const float*)d_in[4];
  const float* Wk  = (const float*)d_in[5];
  const float* bk  = (const float*)d_in[6];
  const float* Wv  = (const float*)d_in[7];
  const float* bv  = (const float*)d_in[8];
  const float* Wo  = (const float*)d_in[9];
  const float* bo  = (const float*)d_in[10];
  float* out = (float*)d_out;
  char* ws = (char*)d_ws;

  const long n4_tgt = (long)8192 * 1024 / 4;
  const long n4_sv  = (long)4096 * 4096 / 4;

  if (ws_size < (132ul << 20)) return;

  bf16* WqT  = (bf16*)(ws + (0l   << 20));  // 2 MB
  bf16* WkT  = (bf16*)(ws + (2l   << 20));  // 8 MB
  bf16* WvT  = (bf16*)(ws + (10l  << 20));  // 8 MB
  bf16* WoT  = (bf16*)(ws + (18l  << 20));  // 2 MB
  bf16* tgtb = (bf16*)(ws + (20l  << 20));  // 16 MB (attn out aliases later)
  bf16* srcb = (bf16*)(ws + (36l  << 20));  // 32 MB
  bf16* valb = (bf16*)(ws + (68l  << 20));  // 32 MB
  bf16* qb   = (bf16*)(ws + (100l << 20));  // 16 MB
  bf16* kb   = (bf16*)(ws + (116l << 20));  // 8 MB
  bf16* vTb  = (bf16*)(ws + (124l << 20));  // 8 MB [4][1024][1024] -> 132 MB
  bf16* attnb = tgtb;  // tgtb dead after QKV gemm

  transpose_cvt_w<<<10240, 256, 0, stream>>>(Wq, WqT, Wk, WkT, Wv, WvT, Wo, WoT);
  cvt3<<<4096, 256, 0, stream>>>(tgt, tgtb, n4_tgt, src, srcb, n4_sv, val, valb, n4_sv);
  // segments: K-proj (256 blocks), V-proj->vT (256), Q-proj (512)
  gemm_qkv<<<1024, 256, 0, stream>>>(srcb, WkT, bk, kb, 4096, 256,
                                     valb, WvT, bv, vTb, 4096, 256,
                                     tgtb, WqT, bq, qb, 1024);
  attn_fused<<<2048, 256, 0, stream>>>(qb, kb, vTb, attnb);
  gemm_bt<<<512, 256, 0, stream>>>(attnb, WoT, bo, (bf16*)nullptr, out, 1024, 1024);
}